// Round 12
// baseline (147.121 us; speedup 1.0000x reference)
//
#include <hip/hip_runtime.h>

#define BB 8
#define TT 2048
#define CC 1024
#define HH 64
#define MM (BB * TT)   // 16384 rows

typedef _Float16 half8 __attribute__((ext_vector_type(8)));
typedef _Float16 half4 __attribute__((ext_vector_type(4)));
typedef float floatx4 __attribute__((ext_vector_type(4)));

// 16-lane all-reduce max via DPP row-rotate butterfly (VALU pipe, no LDS).
template <int CTRL>
__device__ __forceinline__ float dpp_max_step(float x)
{
    union { float f; int i; } u, v;
    u.f = x;
    v.i = __builtin_amdgcn_update_dpp(u.i, u.i, CTRL, 0xf, 0xf, false);
    return fmaxf(x, v.f);
}
__device__ __forceinline__ float rowmax16(float x)
{
    x = dpp_max_step<0x128>(x);   // ROW_ROR:8
    x = dpp_max_step<0x124>(x);   // ROW_ROR:4
    x = dpp_max_step<0x122>(x);   // ROW_ROR:2
    x = dpp_max_step<0x121>(x);   // ROW_ROR:1
    return x;
}

// async global->LDS, 16B per lane; LDS dest is wave-uniform base + lane*16.
__device__ __forceinline__ void gll16h(const _Float16* g, _Float16* l)
{
    __builtin_amdgcn_global_load_lds(
        (const __attribute__((address_space(1))) unsigned int*)g,
        (__attribute__((address_space(3))) unsigned int*)l, 16, 0, 0);
}

#define MEMFENCE asm volatile("" ::: "memory")

// ---------------------------------------------------------------------------
// Kernel 0: pack W into LANE-MAJOR fragment layout:
//   fragment f = c*12 + nf (c = k32-chunk, nf = col/16), 1 KB contiguous:
//   Wp[f*512 + l*8 .. +7] = Wscaled[col = nf*16 + (l&15)][k = c*32 + (l>>4)*8]
// cols 0..63 = Wq*8 (sqrt(H) fold), 64..127 = Wk, 128..191 = Wv.
// ---------------------------------------------------------------------------
__global__ __launch_bounds__(256)
void w_pack(const float* __restrict__ Wk, const float* __restrict__ Wq,
            const float* __restrict__ Wv, _Float16* __restrict__ Wp)
{
    const int T   = blockIdx.x * 256 + threadIdx.x;   // 0..24575
    const int c   = T / 768;           // k-chunk 0..31
    const int rem = T - c * 768;
    const int nf  = rem >> 6;          // col fragment 0..11
    const int l   = rem & 63;          // lane within fragment
    const int col = nf * 16 + (l & 15);
    const int k   = c * 32 + (l >> 4) * 8;
    const int which = col >> 6;
    const float* __restrict__ src = (which == 0) ? Wq : ((which == 1) ? Wk : Wv);
    const float scale = (which == 0) ? 8.0f : 1.0f;
    const int srow = col & 63;
    const float4 a = *reinterpret_cast<const float4*>(&src[srow * 1024 + k]);
    const float4 b = *reinterpret_cast<const float4*>(&src[srow * 1024 + k + 4]);
    const half8 o = { (_Float16)(a.x * scale), (_Float16)(a.y * scale),
                      (_Float16)(a.z * scale), (_Float16)(a.w * scale),
                      (_Float16)(b.x * scale), (_Float16)(b.y * scale),
                      (_Float16)(b.z * scale), (_Float16)(b.w * scale) };
    *reinterpret_cast<half8*>(&Wp[(size_t)T * 8]) = o;
}

// ---------------------------------------------------------------------------
// Kernel 1: QKV projection, v13-FIXED — BK=64, 16 iterations.
// R11 failure root cause: no fence between the 3 W-glls and the 8 plain
// x-loads -> LLVM may reorder plain loads (no LDS alias) before the gll
// intrinsics -> vmcnt(8) no longer forces the W-glls at the barrier ->
// stale W fragments read from LDS (race). FIX: MEMFENCE pins FIFO order
// [3 W-glls | 8 x-loads], making vmcnt(8) exact.
// Structure: W LDS ring-2 (24 KB/slot, lane-major frags, 3 glls/wave/iter);
// x register depth-1 dbuf (8 float4/wave/iter, L1-hot across wn-waves);
// 256 blocks x 8 waves; 16 barrier-synced iterations (was 32 at ~2750
// cy/iter across v7/v10/v12 regardless of instruction count).
// ---------------------------------------------------------------------------
__global__ __launch_bounds__(512, 1)
void qkv13(const float* __restrict__ x, const _Float16* __restrict__ Wp,
           _Float16* __restrict__ q16, _Float16* __restrict__ Kp,
           _Float16* __restrict__ Vp)
{
    __shared__ _Float16 Ws[2][12288];    // 48 KB ring-2; slot = 24 x 1KB frags

    const int tid  = threadIdx.x;
    const int lane = tid & 63;
    const int w    = tid >> 6;           // 0..7
    const int blk  = blockIdx.x;         // 0..255
    const int m_base = blk * 64;
    const int fm = lane & 15;
    const int fq = lane >> 4;
    const int fk = fq * 8;
    const int fr = fq * 4;
    const int wm = w >> 2;               // row half: 0,1
    const int wn = w & 3;                // col group: 0..3

    // x row pointers for the wave's two 16-row tiles
    const float* xr0 = &x[(size_t)(m_base + wm * 32 + fm) * CC + fk];
    const float* xr1 = xr0 + 16 * CC;

    // W staging: wave w stages fragments 3w..3w+2 of the 24 per iteration;
    // iteration i covers global fragments 24i .. 24i+23.
    const _Float16* wsrc = Wp + lane * 8;

    floatx4 acc[2][3];
    #pragma unroll
    for (int a = 0; a < 2; ++a)
        #pragma unroll
        for (int n = 0; n < 3; ++n)
            #pragma unroll
            for (int r = 0; r < 4; ++r) acc[a][n][r] = 0.0f;

    float4 xA[8], xB[8];   // [a*4 + sub*2 + h]

#define STAGE_W(i, slot) do {                                                  \
        const size_t fb = (size_t)(24 * (i) + 3 * w) * 512;                    \
        gll16h(wsrc + fb,        &Ws[slot][(3 * w + 0) * 512]);                \
        gll16h(wsrc + fb + 512,  &Ws[slot][(3 * w + 1) * 512]);                \
        gll16h(wsrc + fb + 1024, &Ws[slot][(3 * w + 2) * 512]);                \
    } while (0)

#define LOAD_X(i, XB) do {                                                     \
        _Pragma("unroll")                                                      \
        for (int a = 0; a < 2; ++a) {                                          \
            const float* xr = a ? xr1 : xr0;                                   \
            _Pragma("unroll")                                                  \
            for (int sub = 0; sub < 2; ++sub) {                                \
                XB[a * 4 + sub * 2 + 0] = *reinterpret_cast<const float4*>(    \
                    xr + (i) * 64 + sub * 32);                                 \
                XB[a * 4 + sub * 2 + 1] = *reinterpret_cast<const float4*>(    \
                    xr + (i) * 64 + sub * 32 + 4);                             \
            }                                                                  \
        }                                                                      \
    } while (0)

#define COMPUTE(sl, XB) do {                                                   \
        half8 wf[2][3];                                                        \
        _Pragma("unroll")                                                      \
        for (int sub = 0; sub < 2; ++sub)                                      \
            _Pragma("unroll")                                                  \
            for (int n = 0; n < 3; ++n)                                        \
                wf[sub][n] = *reinterpret_cast<const half8*>(                  \
                    &Ws[sl][(sub * 12 + wn * 3 + n) * 512 + lane * 8]);        \
        _Pragma("unroll")                                                      \
        for (int a = 0; a < 2; ++a)                                            \
            _Pragma("unroll")                                                  \
            for (int sub = 0; sub < 2; ++sub) {                                \
                const float4 v0 = XB[a * 4 + sub * 2 + 0];                     \
                const float4 v1 = XB[a * 4 + sub * 2 + 1];                     \
                const half8 af = { (_Float16)v0.x, (_Float16)v0.y,             \
                                   (_Float16)v0.z, (_Float16)v0.w,             \
                                   (_Float16)v1.x, (_Float16)v1.y,             \
                                   (_Float16)v1.z, (_Float16)v1.w };           \
                _Pragma("unroll")                                              \
                for (int n = 0; n < 3; ++n)                                    \
                    acc[a][n] = __builtin_amdgcn_mfma_f32_16x16x32_f16(        \
                        af, wf[sub][n], acc[a][n], 0, 0, 0);                   \
            }                                                                  \
    } while (0)

    // FIFO-order-pinned iteration: [W-glls | fence | x-loads | fence |
    // compute (LDS only) | vmcnt(8) forces W | barrier]
#define QITER(i, XC, XN) do {                                                  \
        STAGE_W((i) + 1, ((i) + 1) & 1);                                       \
        MEMFENCE;               /* pin: W-glls oldest in vmcnt FIFO */         \
        LOAD_X((i) + 1, XN);                                                   \
        MEMFENCE;                                                              \
        COMPUTE((i) & 1, XC);                                                  \
        asm volatile("s_waitcnt vmcnt(8)" ::: "memory");                       \
        __builtin_amdgcn_s_barrier();                                          \
        MEMFENCE;                                                              \
    } while (0)

    // ---- prologue: W(0) -> slot 0, x(0) -> xA (same order discipline) ----
    MEMFENCE;
    STAGE_W(0, 0);
    MEMFENCE;
    LOAD_X(0, xA);
    MEMFENCE;
    asm volatile("s_waitcnt vmcnt(8)" ::: "memory");   // W(0) done; x(0) flying
    __builtin_amdgcn_s_barrier();
    MEMFENCE;

    for (int ii = 0; ii < 7; ++ii) {
        QITER(2 * ii,     xA, xB);
        QITER(2 * ii + 1, xB, xA);
    }
    QITER(14, xA, xB);              // stages W(15), loads x(15)->xB
    COMPUTE(1, xB);                 // i = 15 (slot 1); compiler waits x(15)

#undef STAGE_W
#undef LOAD_X
#undef COMPUTE
#undef QITER

    // ---- epilogue: col = wn*48 + n*16 + fm, 16-row tile mt ----
    #pragma unroll
    for (int a = 0; a < 2; ++a) {
        const int mt = blk * 4 + wm * 2 + a;
        #pragma unroll
        for (int n = 0; n < 3; ++n) {
            const int col = wn * 48 + n * 16 + fm;
            if (col < 64) {                          // q: row-major
                #pragma unroll
                for (int r = 0; r < 4; ++r)
                    q16[(size_t)(mt * 16 + fr + r) * HH + col] = (_Float16)acc[a][n][r];
            } else if (col < 128) {                  // k: fragment-packed
                const int h = col - 64;
                _Float16* kp = &Kp[(size_t)(mt * 2 + (h >> 5)) * 512 + (h & 31)];
                #pragma unroll
                for (int r = 0; r < 4; ++r)
                    kp[(fr + r) * 32] = (_Float16)acc[a][n][r];
            } else {                                 // v: fragment-packed (transposed)
                const int h = col - 128;
                const half4 pk = { (_Float16)acc[a][n][0], (_Float16)acc[a][n][1],
                                   (_Float16)acc[a][n][2], (_Float16)acc[a][n][3] };
                *reinterpret_cast<half4*>(
                    &Vp[(size_t)((mt >> 2) * 4 + (h >> 4)) * 1024 +
                        ((mt >> 1) & 1) * 512 + fm * 32 + (mt & 1) * 16 + fr]) = pk;
            }
        }
    }
}

// ---------------------------------------------------------------------------
// Kernel 2: attn8 — K/V LDS-shared 4-wave blocks (R10-proven, restored
// verbatim for clean attribution; attn9's counted-vmcnt ring-3 returns next
// round once qkv13 is validated).
// ---------------------------------------------------------------------------
__global__ __launch_bounds__(256, 3)
void attn8(const _Float16* __restrict__ q16, const _Float16* __restrict__ Kp,
           const _Float16* __restrict__ Vp, float* __restrict__ out,
           _Float16* __restrict__ Op, float* __restrict__ ml)
{
    __shared__ _Float16 Kls[2][4][1024];   // 16 KB: [buf][nt][piece*512 + slot]
    __shared__ _Float16 Vls[2][4][1024];   // 16 KB: [buf][ht][ch*512 + slot]
    __shared__ _Float16 Ps[4][16 * 68];    // 8.7 KB, per-wave private

    const int bid = blockIdx.x;           // 0..767
    const int g   = 31 - bid / 24;        // tile-group, longest first
    const int sub = bid - (31 - g) * 24;
    const int b   = sub & 7;
    const int s   = sub >> 3;             // segment 0..2

    const int tid  = threadIdx.x;
    const int lane = tid & 63;
    const int w    = tid >> 6;            // 0..3
    const int it   = g * 4 + w;           // this wave's q-tile
    const int fm = lane & 15;
    const int fq = lane >> 4;
    const int fk = fq * 8;
    const int fr = fq * 4;

    const int Ji = g + 1;                 // == (it>>2)+1, uniform in block
    const int qq = Ji / 3, rem = Ji - qq * 3;
    const int cnt   = qq + (s < rem ? 1 : 0);
    const int start = s * qq + (s < rem ? s : rem);

    const _Float16* __restrict__ kpb = Kp + (size_t)b * TT * HH;
    const _Float16* __restrict__ vpb = Vp + (size_t)b * TT * HH;

    const int qrow = (b * 128 + it) * 16 + fm;
    const half8 qf0 = *reinterpret_cast<const half8*>(&q16[(size_t)qrow * HH + fk]);
    const half8 qf1 = *reinterpret_cast<const half8*>(&q16[(size_t)qrow * HH + 32 + fk]);

    floatx4 O[4], lacc;
    float m_r[4];
    #pragma unroll
    for (int r = 0; r < 4; ++r) {
        m_r[r] = -3.0e38f;
        lacc[r] = 0.0f;
        #pragma unroll
        for (int ht = 0; ht < 4; ++ht) O[ht][r] = 0.0f;
    }
    const half8 ones = { (_Float16)1.f, (_Float16)1.f, (_Float16)1.f, (_Float16)1.f,
                         (_Float16)1.f, (_Float16)1.f, (_Float16)1.f, (_Float16)1.f };

    // stage-source permutation: LDS slot l receives fragment slot s(l)
    const int sperm = ((lane & 15) * 4 + (lane >> 4)) * 8;   // halves

    if (cnt > 0) {
        // ---- prologue: stage jj = start into buf 0 (4 glls per wave) ----
        {
            const _Float16* kgp = &kpb[(size_t)(start * 4 + w) * 1024];
            const _Float16* vgp = &vpb[(size_t)(start * 4 + w) * 1024];
            gll16h(kgp + sperm,       &Kls[0][w][0]);
            gll16h(kgp + 512 + sperm, &Kls[0][w][512]);
            gll16h(vgp + sperm,       &Vls[0][w][0]);
            gll16h(vgp + 512 + sperm, &Vls[0][w][512]);
        }
        asm volatile("s_waitcnt vmcnt(0)" ::: "memory");
        __builtin_amdgcn_s_barrier();
        MEMFENCE;

        int buf = 0;
        for (int js = 0; js < cnt; ++js) {
            const int jj = start + js;

            // ---- stage jj+1 into buf^1 while computing jj ----
            if (js + 1 < cnt) {
                const _Float16* kgp = &kpb[(size_t)((jj + 1) * 4 + w) * 1024];
                const _Float16* vgp = &vpb[(size_t)((jj + 1) * 4 + w) * 1024];
                gll16h(kgp + sperm,       &Kls[buf ^ 1][w][0]);
                gll16h(kgp + 512 + sperm, &Kls[buf ^ 1][w][512]);
                gll16h(vgp + sperm,       &Vls[buf ^ 1][w][0]);
                gll16h(vgp + 512 + sperm, &Vls[buf ^ 1][w][512]);
            }
            MEMFENCE;

            // ---- S = Q K^T : 8 MFMAs, B-frags linear from LDS ----
            floatx4 sa[4];
            #pragma unroll
            for (int nt = 0; nt < 4; ++nt) {
                #pragma unroll
                for (int r = 0; r < 4; ++r) sa[nt][r] = 0.0f;
                const half8 b0 = *reinterpret_cast<const half8*>(&Kls[buf][nt][lane * 8]);
                const half8 b1 = *reinterpret_cast<const half8*>(&Kls[buf][nt][512 + lane * 8]);
                sa[nt] = __builtin_amdgcn_mfma_f32_16x16x32_f16(qf0, b0, sa[nt], 0, 0, 0);
                sa[nt] = __builtin_amdgcn_mfma_f32_16x16x32_f16(qf1, b1, sa[nt], 0, 0, 0);
            }

            // ---- causal mask (diagonal 64-col block; per-wave rows) ----
            if (jj == g) {
                const int rbase = it * 16 + fr;
                #pragma unroll
                for (int nt = 0; nt < 4; ++nt) {
                    const int col = jj * 64 + nt * 16 + fm;
                    #pragma unroll
                    for (int r = 0; r < 4; ++r)
                        if (col > rbase + r) sa[nt][r] = -3.0e38f;
                }
            }

            // ---- online softmax: DPP row-max; row-sum via ones-MFMA ----
            #pragma unroll
            for (int r = 0; r < 4; ++r) {
                float mx = fmaxf(fmaxf(sa[0][r], sa[1][r]), fmaxf(sa[2][r], sa[3][r]));
                mx = rowmax16(mx);
                const float mn = fmaxf(m_r[r], mx);
                const float alpha = __expf(m_r[r] - mn);
                m_r[r] = mn;
                _Float16* pp = &Ps[w][(fr + r) * 68 + fm];
                pp[0]  = (_Float16)__expf(sa[0][r] - mn);
                pp[16] = (_Float16)__expf(sa[1][r] - mn);
                pp[32] = (_Float16)__expf(sa[2][r] - mn);
                pp[48] = (_Float16)__expf(sa[3][r] - mn);
                lacc[r] *= alpha;
                O[0][r] *= alpha; O[1][r] *= alpha; O[2][r] *= alpha; O[3][r] *= alpha;
            }
            // wave-private Ps: lgkmcnt ordering suffices, no barrier

            // ---- O += P V, l += P 1 : 10 MFMAs, V linear from LDS ----
            #pragma unroll
            for (int ch = 0; ch < 2; ++ch) {
                const half8 pa = *reinterpret_cast<const half8*>(&Ps[w][fm * 68 + ch * 32 + fk]);
                lacc = __builtin_amdgcn_mfma_f32_16x16x32_f16(pa, ones, lacc, 0, 0, 0);
                #pragma unroll
                for (int ht = 0; ht < 4; ++ht) {
                    const half8 vb = *reinterpret_cast<const half8*>(
                        &Vls[buf][ht][ch * 512 + lane * 8]);
                    O[ht] = __builtin_amdgcn_mfma_f32_16x16x32_f16(pa, vb, O[ht], 0, 0, 0);
                }
            }

            // ---- step end: own stage-glls drained, then block barrier ----
            asm volatile("s_waitcnt vmcnt(0)" ::: "memory");
            __builtin_amdgcn_s_barrier();
            MEMFENCE;
            buf ^= 1;
        }
    }

    // ---- epilogue: write segment partial (unnormalized O, m, l) ----
    #pragma unroll
    for (int r = 0; r < 4; ++r) {
        const int grow = (b * 128 + it) * 16 + fr + r;
        if (s == 0) {
            #pragma unroll
            for (int ht = 0; ht < 4; ++ht)
                out[(size_t)grow * HH + ht * 16 + fm] = O[ht][r];
        } else {
            #pragma unroll
            for (int ht = 0; ht < 4; ++ht)
                Op[((size_t)(s - 1) * MM + grow) * HH + ht * 16 + fm] = (_Float16)O[ht][r];
        }
        if (fm == 0) {
            ml[((size_t)s * MM + grow) * 2 + 0] = m_r[r];
            ml[((size_t)s * MM + grow) * 2 + 1] = lacc[r];
        }
    }
}

// ---------------------------------------------------------------------------
// Kernel 3: flash-decode combine of the 3 segment partials.
// ---------------------------------------------------------------------------
__global__ __launch_bounds__(256)
void combine(float* __restrict__ out, const _Float16* __restrict__ Op,
             const float* __restrict__ ml)
{
    const int tid  = threadIdx.x;
    const int grow = blockIdx.x * 64 + (tid >> 2);
    const int c0   = (tid & 3) * 16;

    const float m0 = ml[(size_t)grow * 2 + 0];
    const float l0 = ml[(size_t)grow * 2 + 1];
    const float m1 = ml[((size_t)MM + grow) * 2 + 0];
    const float l1 = ml[((size_t)MM + grow) * 2 + 1];
    const float m2 = ml[((size_t)2 * MM + grow) * 2 + 0];
    const float l2 = ml[((size_t)2 * MM + grow) * 2 + 1];

    const float M  = fmaxf(m0, fmaxf(m1, m2));
    const float w0 = __expf(m0 - M);
    const float w1 = __expf(m1 - M);
    const float w2 = __expf(m2 - M);
    const float inv = 1.0f / (w0 * l0 + w1 * l1 + w2 * l2);

    #pragma unroll
    for (int i = 0; i < 16; i += 4) {
        float4 o0 = *reinterpret_cast<float4*>(&out[(size_t)grow * HH + c0 + i]);
        const half4 h1 = *reinterpret_cast<const half4*>(&Op[(size_t)grow * HH + c0 + i]);
        const half4 h2 = *reinterpret_cast<const half4*>(&Op[(size_t)MM * HH + (size_t)grow * HH + c0 + i]);
        o0.x = (w0 * o0.x + w1 * (float)h1[0] + w2 * (float)h2[0]) * inv;
        o0.y = (w0 * o0.y + w1 * (float)h1[1] + w2 * (float)h2[1]) * inv;
        o0.z = (w0 * o0.z + w1 * (float)h1[2] + w2 * (float)h2[2]) * inv;
        o0.w = (w0 * o0.w + w1 * (float)h1[3] + w2 * (float)h2[3]) * inv;
        *reinterpret_cast<float4*>(&out[(size_t)grow * HH + c0 + i]) = o0;
    }
}

// ---------------------------------------------------------------------------
extern "C" void kernel_launch(void* const* d_in, const int* in_sizes, int n_in,
                              void* d_out, int out_size, void* d_ws, size_t ws_size,
                              hipStream_t stream)
{
    (void)in_sizes; (void)n_in; (void)out_size; (void)ws_size;

    const float* x  = (const float*)d_in[0];
    const float* Wk = (const float*)d_in[1];
    const float* Wq = (const float*)d_in[2];
    const float* Wv = (const float*)d_in[3];
    float* out = (float*)d_out;

    _Float16* base = (_Float16*)d_ws;
    _Float16* q16 = base;                                  // MM*HH halves
    _Float16* Kp  = base + (size_t)MM * HH;                // MM*HH
    _Float16* Vp  = base + (size_t)2 * MM * HH;            // MM*HH
    _Float16* Wp  = base + (size_t)3 * MM * HH;            // 192*1024
    _Float16* Op  = Wp + 192 * 1024;                       // 2*MM*HH
    float*    ml  = (float*)(Op + (size_t)2 * MM * HH);    // 3*MM*2 floats

    w_pack<<<dim3(96), dim3(256), 0, stream>>>(Wk, Wq, Wv, Wp);
    qkv13<<<dim3(256), dim3(512), 0, stream>>>(x, Wp, q16, Kp, Vp);
    attn8<<<dim3(768), dim3(256), 0, stream>>>(q16, Kp, Vp, out, Op, ml);
    combine<<<dim3(256), dim3(256), 0, stream>>>(out, Op, ml);
}